// Round 2
// baseline (315.586 us; speedup 1.0000x reference)
//
#include <hip/hip_runtime.h>

#define KS   13
#define HALF 6
#define TX   64
#define TY   64
#define SH_H (TY + KS - 1)   // 76
#define SH_W 68              // 64 cols + 4 pad floats (bank rotation, keeps 16B align)
#define IMG_H 1024
#define IMG_W 1024

__device__ __forceinline__ int reflect_idx(int i, int n) {
    // single-bounce reflect (offsets <= 8 << n)
    if (i < 0) i = -i;
    if (i >= n) i = 2 * n - 2 - i;
    return i;
}

__global__ __launch_bounds__(256, 6) void gauss_blur_fused(
    const float* __restrict__ x, const float* __restrict__ k2d,
    float* __restrict__ out)
{
    __shared__ float s_h[SH_H][SH_W];   // 76*68*4 = 20672 B

    const int tid = threadIdx.x;
    const int bx  = blockIdx.x;
    const int ox  = bx * TX;
    const int oy  = blockIdx.y * TY;
    const int img = blockIdx.z;

    const float* xin = x + (size_t)img * IMG_H * IMG_W;
    float*       o   = out + (size_t)img * IMG_H * IMG_W;

    // per-thread 1D taps: k2d = outer(g,g) exactly, g[i] = k2d[i][6]/sqrt(k2d[6][6])
    float g[KS];
    {
        float c   = k2d[HALF * KS + HALF];
        float inv = 1.0f / sqrtf(c);
        #pragma unroll
        for (int j = 0; j < KS; ++j) g[j] = k2d[j * KS + HALF] * inv;
    }

    const bool interior = (bx > 0) && (bx < (IMG_W / TX) - 1);

    // ---- Phase 1: horizontal 13-tap pass, global -> registers -> s_h ----
    // 76 rows x 8 col-groups (8 outputs each) = 608 tasks
    for (int idx = tid; idx < SH_H * 8; idx += 256) {
        int r    = idx >> 3;
        int t8   = idx & 7;
        int gr   = reflect_idx(oy + r - HALF, IMG_H);
        const float* row = xin + (size_t)gr * IMG_W;
        int base = ox - 8 + t8 * 8;     // rin[i] <-> col base+i, i in [0,24)

        float rin[24];
        if (interior) {
            #pragma unroll
            for (int i = 0; i < 6; ++i) {
                float4 v = *reinterpret_cast<const float4*>(row + base + 4 * i);
                rin[4*i+0] = v.x; rin[4*i+1] = v.y;
                rin[4*i+2] = v.z; rin[4*i+3] = v.w;
            }
        } else {
            #pragma unroll
            for (int i = 0; i < 24; ++i)
                rin[i] = row[reflect_idx(base + i, IMG_W)];
        }

        float acc[8];
        #pragma unroll
        for (int u = 0; u < 8; ++u) acc[u] = 0.0f;
        #pragma unroll
        for (int j = 0; j < KS; ++j) {
            #pragma unroll
            for (int u = 0; u < 8; ++u)
                acc[u] += g[j] * rin[u + 2 + j];   // output col ox+t8*8+u, taps c-6..c+6
        }

        float4* dst = reinterpret_cast<float4*>(&s_h[r][t8 * 8]);
        dst[0] = make_float4(acc[0], acc[1], acc[2], acc[3]);
        dst[1] = make_float4(acc[4], acc[5], acc[6], acc[7]);
    }
    __syncthreads();

    // ---- Phase 2: vertical 13-tap pass, s_h -> registers -> global ----
    // each thread: 4 rows x 4 cols
    {
        int cg = tid & 15;
        int rg = tid >> 4;
        int c  = cg * 4;
        int r0 = rg * 4;

        float4 acc[4];
        #pragma unroll
        for (int ii = 0; ii < 4; ++ii) acc[ii] = make_float4(0, 0, 0, 0);

        #pragma unroll
        for (int i = 0; i < KS + 3; ++i) {   // 16 rows: r0 .. r0+15
            float4 v = *reinterpret_cast<const float4*>(&s_h[r0 + i][c]);
            #pragma unroll
            for (int ii = 0; ii < 4; ++ii) {
                int j = i - ii;
                if (j >= 0 && j < KS) {
                    acc[ii].x += g[j] * v.x;
                    acc[ii].y += g[j] * v.y;
                    acc[ii].z += g[j] * v.z;
                    acc[ii].w += g[j] * v.w;
                }
            }
        }

        #pragma unroll
        for (int ii = 0; ii < 4; ++ii)
            *reinterpret_cast<float4*>(o + (size_t)(oy + r0 + ii) * IMG_W + ox + c) = acc[ii];
    }
}

extern "C" void kernel_launch(void* const* d_in, const int* in_sizes, int n_in,
                              void* d_out, int out_size, void* d_ws, size_t ws_size,
                              hipStream_t stream) {
    const float* x   = (const float*)d_in[0];
    const float* k2d = (const float*)d_in[1];
    float*       out = (float*)d_out;

    dim3 grid(IMG_W / TX, IMG_H / TY, 32);  // 16 x 16 x 32 = 8192 blocks
    gauss_blur_fused<<<grid, 256, 0, stream>>>(x, k2d, out);
}

// Round 3
// 170.477 us; speedup vs baseline: 1.8512x; 1.8512x over previous
//
#include <hip/hip_runtime.h>

#define KS   13
#define HALF 6
#define TX   64
#define TY   64
#define SH_H (TY + KS - 1)   // 76
#define SH_W 68              // 64 cols + 4 pad floats (keeps 16B align, rotates banks)
#define IMG_H 1024
#define IMG_W 1024

__device__ __forceinline__ int reflect_idx(int i, int n) {
    // single-bounce reflect (offsets <= 8 << n)
    if (i < 0) i = -i;
    if (i >= n) i = 2 * n - 2 - i;
    return i;
}

// (256,4): min 4 waves/EU -> VGPR cap 128. The (256,6) variant capped VGPRs at 40
// and spilled rin[24]+acc[8]+g[13] to scratch: WRITE_SIZE 543 MB, 3x slowdown.
__global__ __launch_bounds__(256, 4) void gauss_blur_fused(
    const float* __restrict__ x, const float* __restrict__ k2d,
    float* __restrict__ out)
{
    __shared__ float s_h[SH_H][SH_W];   // 76*68*4 = 20672 B

    const int tid = threadIdx.x;
    const int bx  = blockIdx.x;
    const int ox  = bx * TX;
    const int oy  = blockIdx.y * TY;
    const int img = blockIdx.z;

    const float* xin = x + (size_t)img * IMG_H * IMG_W;
    float*       o   = out + (size_t)img * IMG_H * IMG_W;

    // per-thread 1D taps: k2d = outer(g,g) exactly, g[i] = k2d[i][6]/sqrt(k2d[6][6])
    float g[KS];
    {
        float c   = k2d[HALF * KS + HALF];
        float inv = 1.0f / sqrtf(c);
        #pragma unroll
        for (int j = 0; j < KS; ++j) g[j] = k2d[j * KS + HALF] * inv;
    }

    const bool interior = (bx > 0) && (bx < (IMG_W / TX) - 1);

    // ---- Phase 1: horizontal 13-tap pass, global -> registers -> s_h ----
    // 76 rows x 8 col-groups (8 outputs each) = 608 tasks
    for (int idx = tid; idx < SH_H * 8; idx += 256) {
        int r    = idx >> 3;
        int t8   = idx & 7;
        int gr   = reflect_idx(oy + r - HALF, IMG_H);
        const float* row = xin + (size_t)gr * IMG_W;
        int base = ox - 8 + t8 * 8;     // rin[i] <-> col base+i, i in [0,24)

        float rin[24];
        if (interior) {
            #pragma unroll
            for (int i = 0; i < 6; ++i) {
                float4 v = *reinterpret_cast<const float4*>(row + base + 4 * i);
                rin[4*i+0] = v.x; rin[4*i+1] = v.y;
                rin[4*i+2] = v.z; rin[4*i+3] = v.w;
            }
        } else {
            #pragma unroll
            for (int i = 0; i < 24; ++i)
                rin[i] = row[reflect_idx(base + i, IMG_W)];
        }

        float acc[8];
        #pragma unroll
        for (int u = 0; u < 8; ++u) acc[u] = 0.0f;
        #pragma unroll
        for (int j = 0; j < KS; ++j) {
            #pragma unroll
            for (int u = 0; u < 8; ++u)
                acc[u] += g[j] * rin[u + 2 + j];   // output col ox+t8*8+u, taps c-6..c+6
        }

        float4* dst = reinterpret_cast<float4*>(&s_h[r][t8 * 8]);
        dst[0] = make_float4(acc[0], acc[1], acc[2], acc[3]);
        dst[1] = make_float4(acc[4], acc[5], acc[6], acc[7]);
    }
    __syncthreads();

    // ---- Phase 2: vertical 13-tap pass, s_h -> registers -> global ----
    // each thread: 4 rows x 4 cols
    {
        int cg = tid & 15;
        int rg = tid >> 4;
        int c  = cg * 4;
        int r0 = rg * 4;

        float4 acc[4];
        #pragma unroll
        for (int ii = 0; ii < 4; ++ii) acc[ii] = make_float4(0, 0, 0, 0);

        #pragma unroll
        for (int i = 0; i < KS + 3; ++i) {   // 16 rows: r0 .. r0+15
            float4 v = *reinterpret_cast<const float4*>(&s_h[r0 + i][c]);
            #pragma unroll
            for (int ii = 0; ii < 4; ++ii) {
                int j = i - ii;
                if (j >= 0 && j < KS) {
                    acc[ii].x += g[j] * v.x;
                    acc[ii].y += g[j] * v.y;
                    acc[ii].z += g[j] * v.z;
                    acc[ii].w += g[j] * v.w;
                }
            }
        }

        #pragma unroll
        for (int ii = 0; ii < 4; ++ii)
            *reinterpret_cast<float4*>(o + (size_t)(oy + r0 + ii) * IMG_W + ox + c) = acc[ii];
    }
}

extern "C" void kernel_launch(void* const* d_in, const int* in_sizes, int n_in,
                              void* d_out, int out_size, void* d_ws, size_t ws_size,
                              hipStream_t stream) {
    const float* x   = (const float*)d_in[0];
    const float* k2d = (const float*)d_in[1];
    float*       out = (float*)d_out;

    dim3 grid(IMG_W / TX, IMG_H / TY, 32);  // 16 x 16 x 32 = 8192 blocks
    gauss_blur_fused<<<grid, 256, 0, stream>>>(x, k2d, out);
}

// Round 4
// 81.806 us; speedup vs baseline: 3.8578x; 2.0839x over previous
//
#include <hip/hip_runtime.h>

#define KS   13
#define HALF 6
#define TX   64
#define TY   64
#define SI_H 76          // TY + 12
#define SI_W 80          // TX + 16 (halo 8 each side, float4 granularity)
#define SI_P 84          // pitch: 336B, 16B-aligned; row bank-shift 20 -> even granule spread
#define SH_H 76
#define SH_P 68          // pitch: 272B, 16B-aligned; verified even 8-lanes/granule on V reads
#define IMG_H 1024
#define IMG_W 1024

__device__ __forceinline__ int reflect_idx(int i, int n) {
    // single-bounce reflect (offsets <= 8 << n)
    if (i < 0) i = -i;
    if (i >= n) i = 2 * n - 2 - i;
    return i;
}

// No min-waves bound: (256,6) capped VGPR at 40 and spilled (543 MB scratch writes).
__global__ __launch_bounds__(256) void gauss_blur_fused(
    const float* __restrict__ x, const float* __restrict__ k2d,
    float* __restrict__ out)
{
    __shared__ float s_in[SI_H][SI_P];  // 76*84*4 = 25536 B
    __shared__ float s_h [SH_H][SH_P];  // 76*68*4 = 20672 B

    const int tid = threadIdx.x;
    const int bx  = blockIdx.x;
    const int ox  = bx * TX;
    const int oy  = blockIdx.y * TY;
    const int img = blockIdx.z;

    const float* xin = x + (size_t)img * IMG_H * IMG_W;
    float*       o   = out + (size_t)img * IMG_H * IMG_W;

    // per-thread 1D taps: k2d = outer(g,g) exactly, g[i] = k2d[i][6]/sqrt(k2d[6][6])
    float g[KS];
    {
        float c   = k2d[HALF * KS + HALF];
        float inv = 1.0f / sqrtf(c);
        #pragma unroll
        for (int j = 0; j < KS; ++j) g[j] = k2d[j * KS + HALF] * inv;
    }

    const bool interior = (bx > 0) && (bx < (IMG_W / TX) - 1);

    // ---- Stage: global -> s_in, fully coalesced float4 (16B/lane consecutive) ----
    // 76 rows x 20 float4 groups = 1520 tasks
    for (int idx = tid; idx < SI_H * (SI_W / 4); idx += 256) {
        int r   = idx / (SI_W / 4);
        int c4  = idx - r * (SI_W / 4);
        int gr  = reflect_idx(oy + r - HALF, IMG_H);
        const float* row = xin + (size_t)gr * IMG_W;
        int gc0 = ox - 8 + c4 * 4;
        float4 v;
        if (interior) {
            v = *reinterpret_cast<const float4*>(row + gc0);
        } else {
            v.x = row[reflect_idx(gc0 + 0, IMG_W)];
            v.y = row[reflect_idx(gc0 + 1, IMG_W)];
            v.z = row[reflect_idx(gc0 + 2, IMG_W)];
            v.w = row[reflect_idx(gc0 + 3, IMG_W)];
        }
        *reinterpret_cast<float4*>(&s_in[r][c4 * 4]) = v;
    }
    __syncthreads();

    // ---- H pass: s_in -> registers -> s_h. 8 outputs per task, 6 ds_read_b128 ----
    // 76 rows x 8 groups = 608 tasks
    for (int idx = tid; idx < SI_H * 8; idx += 256) {
        int r  = idx >> 3;
        int g8 = (idx & 7) * 8;

        float w[24];
        #pragma unroll
        for (int k = 0; k < 6; ++k) {
            float4 v = *reinterpret_cast<const float4*>(&s_in[r][g8 + 4 * k]);
            w[4*k+0] = v.x; w[4*k+1] = v.y; w[4*k+2] = v.z; w[4*k+3] = v.w;
        }

        float acc[8];
        #pragma unroll
        for (int u = 0; u < 8; ++u) acc[u] = 0.0f;
        #pragma unroll
        for (int j = 0; j < KS; ++j) {
            #pragma unroll
            for (int u = 0; u < 8; ++u)
                acc[u] += g[j] * w[u + 2 + j];   // out col ox+g8+u <- s_in cols g8+u+2+j
        }

        float4* dst = reinterpret_cast<float4*>(&s_h[r][g8]);
        dst[0] = make_float4(acc[0], acc[1], acc[2], acc[3]);
        dst[1] = make_float4(acc[4], acc[5], acc[6], acc[7]);
    }
    __syncthreads();

    // ---- V pass: s_h -> registers -> global. 16 outputs (4x4) per thread ----
    {
        int c  = (tid & 15) * 4;
        int r0 = (tid >> 4) * 4;

        float4 acc[4];
        #pragma unroll
        for (int ii = 0; ii < 4; ++ii) acc[ii] = make_float4(0, 0, 0, 0);

        #pragma unroll
        for (int i = 0; i < KS + 3; ++i) {   // 16 rows: r0 .. r0+15
            float4 v = *reinterpret_cast<const float4*>(&s_h[r0 + i][c]);
            #pragma unroll
            for (int ii = 0; ii < 4; ++ii) {
                int j = i - ii;
                if (j >= 0 && j < KS) {
                    acc[ii].x += g[j] * v.x;
                    acc[ii].y += g[j] * v.y;
                    acc[ii].z += g[j] * v.z;
                    acc[ii].w += g[j] * v.w;
                }
            }
        }

        #pragma unroll
        for (int ii = 0; ii < 4; ++ii)
            *reinterpret_cast<float4*>(o + (size_t)(oy + r0 + ii) * IMG_W + ox + c) = acc[ii];
    }
}

extern "C" void kernel_launch(void* const* d_in, const int* in_sizes, int n_in,
                              void* d_out, int out_size, void* d_ws, size_t ws_size,
                              hipStream_t stream) {
    const float* x   = (const float*)d_in[0];
    const float* k2d = (const float*)d_in[1];
    float*       out = (float*)d_out;

    dim3 grid(IMG_W / TX, IMG_H / TY, 32);  // 16 x 16 x 32 = 8192 blocks
    gauss_blur_fused<<<grid, 256, 0, stream>>>(x, k2d, out);
}

// Round 5
// 79.313 us; speedup vs baseline: 3.9790x; 1.0314x over previous
//
#include <hip/hip_runtime.h>

#define KS   13
#define HALF 6
#define TX   64
#define TY   64
#define S_H  76
#define S_P  84          // pitch (floats): 20r mod 32 spreads rows; 16B aligned
#define NG   20          // staged float4 granules/row (80 floats: 8 halo + 64 + 8)
#define NTASK (S_H * 16) // 1216 H tasks, 4 outputs each
#define IMG_H 1024
#define IMG_W 1024

__device__ __forceinline__ int reflect_idx(int i, int n) {
    // single-bounce reflect (offsets <= 8 << n)
    if (i < 0) i = -i;
    if (i >= n) i = 2 * n - 2 - i;
    return i;
}

// No min-waves bound: (256,6) capped VGPRs at 40 -> 543 MB scratch spill (R2).
__global__ __launch_bounds__(256) void gauss_blur_fused(
    const float* __restrict__ x, const float* __restrict__ k2d,
    float* __restrict__ out)
{
    // ONE buffer, in-place H: 25536 B -> 6 blocks/CU (was 46.6 KB -> 3)
    __shared__ float s[S_H][S_P];

    const int tid = threadIdx.x;
    const int bx  = blockIdx.x;
    const int ox  = bx * TX;
    const int oy  = blockIdx.y * TY;
    const int img = blockIdx.z;

    const float* xin = x + (size_t)img * IMG_H * IMG_W;
    float*       o   = out + (size_t)img * IMG_H * IMG_W;

    // per-thread 1D taps: k2d = outer(g,g), g[i] = k2d[i][6]/sqrt(k2d[6][6])
    float g[KS];
    {
        float c   = k2d[HALF * KS + HALF];
        float inv = 1.0f / sqrtf(c);
        #pragma unroll
        for (int j = 0; j < KS; ++j) g[j] = k2d[j * KS + HALF] * inv;
    }

    const bool interior = (bx > 0) && (bx < (IMG_W / TX) - 1);

    // ---- Stage: global -> s, coalesced float4. s[r][i] = x[refl(oy+r-6)][ox-8+i] ----
    for (int idx = tid; idx < S_H * NG; idx += 256) {
        int r   = idx / NG;
        int c4  = idx - r * NG;
        int gr  = reflect_idx(oy + r - HALF, IMG_H);
        const float* row = xin + (size_t)gr * IMG_W;
        int gc0 = ox - 8 + c4 * 4;
        float4 v;
        if (interior) {
            v = *reinterpret_cast<const float4*>(row + gc0);
        } else {
            v.x = row[reflect_idx(gc0 + 0, IMG_W)];
            v.y = row[reflect_idx(gc0 + 1, IMG_W)];
            v.z = row[reflect_idx(gc0 + 2, IMG_W)];
            v.w = row[reflect_idx(gc0 + 3, IMG_W)];
        }
        *reinterpret_cast<float4*>(&s[r][c4 * 4]) = v;
    }
    __syncthreads();

    // ---- H pass (reads only): 16 lanes/row x 4 outputs, 5 ds_read_b128/task ----
    // task (r, q): outputs cols 4q..4q+3 <- s[r][4q+2 .. 4q+17] (granules q..q+4)
    float acc[5][4];
    #pragma unroll
    for (int t = 0; t < 5; ++t) {
        int idx = tid + t * 256;
        if (idx < NTASK) {
            int r = idx >> 4;
            int q = idx & 15;
            float w[20];
            #pragma unroll
            for (int k = 0; k < 5; ++k) {
                float4 v = *reinterpret_cast<const float4*>(&s[r][(q + k) * 4]);
                w[4*k+0] = v.x; w[4*k+1] = v.y; w[4*k+2] = v.z; w[4*k+3] = v.w;
            }
            #pragma unroll
            for (int u = 0; u < 4; ++u) acc[t][u] = 0.0f;
            #pragma unroll
            for (int j = 0; j < KS; ++j) {
                #pragma unroll
                for (int u = 0; u < 4; ++u)
                    acc[t][u] += g[j] * w[u + 2 + j];
            }
        }
    }
    __syncthreads();

    // ---- H write-back (in place): H row r -> s[r][8..71] ----
    #pragma unroll
    for (int t = 0; t < 5; ++t) {
        int idx = tid + t * 256;
        if (idx < NTASK) {
            int r = idx >> 4;
            int q = idx & 15;
            *reinterpret_cast<float4*>(&s[r][8 + q * 4]) =
                make_float4(acc[t][0], acc[t][1], acc[t][2], acc[t][3]);
        }
    }
    __syncthreads();

    // ---- V pass: s -> registers -> global. 16 outputs (4x4) per thread ----
    {
        int c  = (tid & 15) * 4 + 8;
        int r0 = (tid >> 4) * 4;

        float4 vacc[4];
        #pragma unroll
        for (int ii = 0; ii < 4; ++ii) vacc[ii] = make_float4(0, 0, 0, 0);

        #pragma unroll
        for (int i = 0; i < KS + 3; ++i) {   // 16 rows: r0 .. r0+15
            float4 v = *reinterpret_cast<const float4*>(&s[r0 + i][c]);
            #pragma unroll
            for (int ii = 0; ii < 4; ++ii) {
                int j = i - ii;
                if (j >= 0 && j < KS) {
                    vacc[ii].x += g[j] * v.x;
                    vacc[ii].y += g[j] * v.y;
                    vacc[ii].z += g[j] * v.z;
                    vacc[ii].w += g[j] * v.w;
                }
            }
        }

        #pragma unroll
        for (int ii = 0; ii < 4; ++ii)
            *reinterpret_cast<float4*>(o + (size_t)(oy + r0 + ii) * IMG_W + ox + (c - 8)) = vacc[ii];
    }
}

extern "C" void kernel_launch(void* const* d_in, const int* in_sizes, int n_in,
                              void* d_out, int out_size, void* d_ws, size_t ws_size,
                              hipStream_t stream) {
    const float* x   = (const float*)d_in[0];
    const float* k2d = (const float*)d_in[1];
    float*       out = (float*)d_out;

    dim3 grid(IMG_W / TX, IMG_H / TY, 32);  // 16 x 16 x 32 = 8192 blocks
    gauss_blur_fused<<<grid, 256, 0, stream>>>(x, k2d, out);
}